// Round 10
// baseline (65.218 us; speedup 1.0000x reference)
//
#include <hip/hip_runtime.h>

#define B_ 32
#define C_ 64
#define N_ 2048
#define D_ 6

#define TPB 256
#define NW  4     // waves per block
#define CPS 16    // capsules per wave
#define PF  8     // votes prefetch depth (iterations)

static __device__ __forceinline__ float2 ld2(const float* p) {
    return *reinterpret_cast<const float2*>(p);
}

// Output layout (flat, return order), all float32
static constexpr long OFF_VP   = 1;
static constexpr long OFF_WIN  = OFF_VP   + (long)B_*C_*N_;
static constexpr long OFF_WINP = OFF_WIN  + (long)B_*N_*D_;
static constexpr long OFF_IFC  = OFF_WINP + (long)B_*N_;
static constexpr long OFF_ML   = OFF_IFC  + (long)B_*N_;
static constexpr long OFF_MLP  = OFF_ML   + (long)B_*(C_+1)*N_;
static constexpr long OFF_SW   = OFF_MLP  + (long)B_*(C_+1)*N_;
static constexpr long OFF_SWP  = OFF_SW   + (long)B_*N_*D_;
static constexpr long OFF_PMP  = OFF_SWP  + (long)B_*N_;
static constexpr long OFF_CAPS = OFF_PMP  + (long)B_*N_*C_;

__global__ __launch_bounds__(TPB, 4) void capsule_main(
    const float* __restrict__ x,
    const float* __restrict__ votes,
    const float* __restrict__ scale,
    const float* __restrict__ vpp,
    const float* __restrict__ dummy_vote,
    float* __restrict__ out)
{
    constexpr float DUMMY       = -4.6051702f;   // -2*ln(10)
    constexpr float HALFDLOG2PI =  5.5136312f;   // 0.5*D*ln(2*pi)

    // XCD-chunked swizzle: default dispatch round-robins XCDs (bid%8 = XCD).
    // Remap so each XCD owns a contiguous 128-block n-range: adjacent-n blocks
    // (sharing input lines + misaligned write-boundary lines) stay in one L2.
    const int bid  = (int)((blockIdx.x & 7) * 128 + (blockIdx.x >> 3));   // bijective, 8|1024

    const int tid  = threadIdx.x;
    const int lane = tid & 63;
    const int sub  = tid >> 6;                    // 0..3
    const int idx  = bid * 64 + lane;             // b*N + n
    const int b    = idx >> 11;                   // N_ == 2048 (no b straddle: 64|2048)
    const int n    = idx & (N_ - 1);

    const size_t base  = (size_t)b * (C_ * N_) + n;
    const size_t soff  = (size_t)(sub * CPS) * N_;
    const float* scp   = scale + base + soff;
    const float* ppp   = vpp   + base + soff;
    const float* vbs   = votes + (base + soff) * D_;
    const size_t mlrow = (size_t)b * ((C_ + 1) * N_) + n;

    // batch-issue all scale/vpp loads upfront (latency batching)
    float sv[CPS], pv[CPS];
#pragma unroll
    for (int j = 0; j < CPS; ++j) {
        sv[j] = scp[(size_t)j * N_];
        pv[j] = ppp[(size_t)j * N_];
    }

    const float* xp = x + (size_t)idx * D_;
    const float2 xa = ld2(xp), xb = ld2(xp + 2), xc = ld2(xp + 4);

    // votes software pipeline, depth PF, static slot indexing
    float2 va0[PF], va1[PF], va2[PF];
#pragma unroll
    for (int j = 0; j < PF; ++j) {
        const float* vp = vbs + (size_t)j * (N_ * D_);
        va0[j] = ld2(vp); va1[j] = ld2(vp + 2); va2[j] = ld2(vp + 4);
    }

    // LDS: lred/lbc for cross-sub combine; lpmp stages unnormalized e; linv per-point 1/sum
    __shared__ float lred[17 * TPB];
    __shared__ int   lbc[TPB];
    __shared__ float lpmp[64 * 65];
    __shared__ float linv[64];

    // sub 0 seeds the dummy contributions
    float s_pp = 0.0f, s_p = 0.0f;
    float sw0 = 0.f, sw1 = 0.f, sw2 = 0.f, sw3 = 0.f, sw4 = 0.f, sw5 = 0.f;
    if (sub == 0) {
        const float* dp = dummy_vote + (size_t)n * D_;
        const float2 da = ld2(dp), db = ld2(dp + 2), dc = ld2(dp + 4);
        s_pp = 0.01f;            // exp(DUMMY)
        s_p  = 1.0e-4f;          // exp(2*DUMMY)
        sw0 = 1.0e-4f * da.x; sw1 = 1.0e-4f * da.y;
        sw2 = 1.0e-4f * db.x; sw3 = 1.0e-4f * db.y;
        sw4 = 1.0e-4f * dc.x; sw5 = 1.0e-4f * dc.y;
    }
    float swp = 0.0f;
    float best = -3.4e38f, winp = 0.0f;
    float w0=0.f,w1=0.f,w2=0.f,w3=0.f,w4=0.f,w5=0.f;
    int bc = 0;

#pragma unroll
    for (int j = 0; j < CPS; ++j) {
        const int c  = sub * CPS + j;
        const int sl = j % PF;
        const float2 A = va0[sl], Bv = va1[sl], Cv = va2[sl];
        if (j + PF < CPS) {                       // compile-time per unrolled iter
            const float* vp = vbs + (size_t)(j + PF) * (N_ * D_);
            va0[sl] = ld2(vp); va1[sl] = ld2(vp + 2); va2[sl] = ld2(vp + 4);
        }
        const float s = sv[j];
        const float p = pv[j];
        const float inv = 1.0f / s;
        const float z0 = (xa.x - A.x)  * inv;
        const float z1 = (xa.y - A.y)  * inv;
        const float z2 = (xb.x - Bv.x) * inv;
        const float z3 = (xb.y - Bv.y) * inv;
        const float z4 = (xc.x - Cv.x) * inv;
        const float z5 = (xc.y - Cv.y) * inv;
        float q = z0 * z0;
        q = fmaf(z1, z1, q); q = fmaf(z2, z2, q);
        q = fmaf(z3, z3, q); q = fmaf(z4, z4, q);
        q = fmaf(z5, z5, q);
        const float vlp = fmaf(-0.5f, q, fmaf(-6.0f, __logf(s), -HALFDLOG2PI));
        const float ml  = __logf(p + 1e-16f);
        out[OFF_ML + mlrow + (size_t)c * N_] = ml;                          // coalesced over n
        out[OFF_VP + ((size_t)(b * C_ + c)) * N_ + n] = (DUMMY < ml) ? 1.0f : 0.0f;
        const float pc = ml + vlp;
        const float e  = __expf(pc);
        lpmp[lane * 65 + c] = e;                  // stage unnormalized; scaled at flush
        s_pp += p + 1e-16f;
        s_p  += e;
        sw0 = fmaf(e, A.x,  sw0); sw1 = fmaf(e, A.y,  sw1);
        sw2 = fmaf(e, Bv.x, sw2); sw3 = fmaf(e, Bv.y, sw3);
        sw4 = fmaf(e, Cv.x, sw4); sw5 = fmaf(e, Cv.y, sw5);
        swp = fmaf(e, p, swp);
        const bool better = pc > best;            // strict > keeps first occurrence
        best = better ? pc : best;
        bc   = better ? c  : bc;
        w0 = better ? A.x  : w0; w1 = better ? A.y  : w1;
        w2 = better ? Bv.x : w2; w3 = better ? Bv.y : w3;
        w4 = better ? Cv.x : w4; w5 = better ? Cv.y : w5;
        winp = better ? p : winp;
    }

    // ---- cross-sub combine via LDS ----
#define LR(e) lred[(e) * TPB + sub * 64 + lane]
    LR(0) = s_p;
    LR(1) = sw0; LR(2) = sw1; LR(3) = sw2; LR(4) = sw3; LR(5) = sw4; LR(6) = sw5;
    LR(7) = swp; LR(8) = s_pp;
    LR(9) = best;
    LR(10) = w0; LR(11) = w1; LR(12) = w2; LR(13) = w3; LR(14) = w4; LR(15) = w5;
    LR(16) = winp;
    lbc[sub * 64 + lane] = bc;
#undef LR
    __syncthreads();

#define LS(e, s) lred[(e) * TPB + (s) * 64 + lane]
    float c_sp  = LS(0,0) + LS(0,1) + LS(0,2) + LS(0,3);
    float c_sw0 = LS(1,0) + LS(1,1) + LS(1,2) + LS(1,3);
    float c_sw1 = LS(2,0) + LS(2,1) + LS(2,2) + LS(2,3);
    float c_sw2 = LS(3,0) + LS(3,1) + LS(3,2) + LS(3,3);
    float c_sw3 = LS(4,0) + LS(4,1) + LS(4,2) + LS(4,3);
    float c_sw4 = LS(5,0) + LS(5,1) + LS(5,2) + LS(5,3);
    float c_sw5 = LS(6,0) + LS(6,1) + LS(6,2) + LS(6,3);
    float c_swp = LS(7,0) + LS(7,1) + LS(7,2) + LS(7,3);
    float c_spp = LS(8,0) + LS(8,1) + LS(8,2) + LS(8,3);
    float g_best = LS(9,0);
    int   g_bc   = lbc[lane];
    float g_w0 = LS(10,0), g_w1 = LS(11,0), g_w2 = LS(12,0),
          g_w3 = LS(13,0), g_w4 = LS(14,0), g_w5 = LS(15,0);
    float g_winp = LS(16,0);
#pragma unroll
    for (int s = 1; s < NW; ++s) {
        const float cb = LS(9, s);
        if (cb > g_best) {                      // strict >: earliest sub wins ties
            g_best = cb;
            g_bc   = lbc[s * 64 + lane];
            g_w0 = LS(10,s); g_w1 = LS(11,s); g_w2 = LS(12,s);
            g_w3 = LS(13,s); g_w4 = LS(14,s); g_w5 = LS(15,s);
            g_winp = LS(16,s);
        }
    }
#undef LS

    const float lse_ml = __logf(c_spp);
    const float lse_p  = __logf(c_sp);
    const float inv_sp = 1.0f / c_sp;

    if (sub == 0) {
        linv[lane] = inv_sp;
        out[OFF_ML  + mlrow + (size_t)C_ * N_] = DUMMY;
        out[OFF_MLP + mlrow + (size_t)C_ * N_] = DUMMY - lse_ml;
        float* wq = out + OFF_WIN + (size_t)idx * D_;
        wq[0] = g_w0; wq[1] = g_w1; wq[2] = g_w2;
        wq[3] = g_w3; wq[4] = g_w4; wq[5] = g_w5;
        out[OFF_WINP + idx] = g_winp;
        out[OFF_IFC + idx]  = 0.0f;               // g_bc < 64 < N -> always 0
        float* sq = out + OFF_SW + (size_t)idx * D_;
        sq[0] = c_sw0 * inv_sp; sq[1] = c_sw1 * inv_sp; sq[2] = c_sw2 * inv_sp;
        sq[3] = c_sw3 * inv_sp; sq[4] = c_sw4 * inv_sp; sq[5] = c_sw5 * inv_sp;
        out[OFF_SWP + idx] = c_swp * inv_sp;
        // per-block lse sum -> one atomicAdd into out[0] (zeroed via memsetAsync each call)
        float v = lse_p;
#pragma unroll
        for (int m = 32; m > 0; m >>= 1)
            v += __shfl_xor(v, m, 64);
        if (lane == 0) atomicAdd(out, v * (1.0f / (float)B_));
    }

    // mixing_log_prob for this sub's capsules (ml recomputed from live pv)
#pragma unroll
    for (int j = 0; j < CPS; ++j) {
        const int c = sub * CPS + j;
        out[OFF_MLP + mlrow + (size_t)c * N_] = __logf(pv[j] + 1e-16f) - lse_ml;
    }

    __syncthreads();   // lpmp complete + linv visible

    // posterior_mixing_probs flush: coalesced, normalized by the owning point's inv_sp
    {
        const size_t pbase = OFF_PMP + (size_t)bid * (64 * C_);
#pragma unroll
        for (int k = 0; k < (64 * C_) / TPB; ++k) {
            const int g = tid + k * TPB;
            const int p = g >> 6, cc = g & 63;
            out[pbase + g] = lpmp[p * 65 + cc] * linv[p];
        }
    }

    // caps_presence: wave-max over this block's 64 n's, then one atomicMax per (sub,c).
    // vpp > 0, so float bits are uint-monotone; region zeroed via memsetAsync each call.
    {
        unsigned int* cp = (unsigned int*)(out + OFF_CAPS) + (b * C_ + sub * CPS);
#pragma unroll
        for (int j = 0; j < CPS; ++j) {
            float m = pv[j];
#pragma unroll
            for (int q2 = 32; q2 > 0; q2 >>= 1)
                m = fmaxf(m, __shfl_xor(m, q2, 64));
            if (lane == 0) atomicMax(cp + j, __float_as_uint(m));
        }
    }
}

extern "C" void kernel_launch(void* const* d_in, const int* in_sizes, int n_in,
                              void* d_out, int out_size, void* d_ws, size_t ws_size,
                              hipStream_t stream) {
    const float* x     = (const float*)d_in[0];
    const float* votes = (const float*)d_in[1];
    const float* scale = (const float*)d_in[2];
    const float* vpp   = (const float*)d_in[3];
    const float* dummy = (const float*)d_in[4];
    float* out = (float*)d_out;

    // zero the atomic targets (log_prob scalar + caps_presence region), graph-capturable
    hipMemsetAsync(out, 0, sizeof(float), stream);
    hipMemsetAsync(out + OFF_CAPS, 0, (size_t)B_ * C_ * sizeof(float), stream);

    capsule_main<<<(B_ * N_) / 64, TPB, 0, stream>>>(x, votes, scale, vpp, dummy, out);
}

// Round 11
// 40.184 us; speedup vs baseline: 1.6230x; 1.6230x over previous
//
#include <hip/hip_runtime.h>

#define B_ 32
#define C_ 64
#define N_ 2048
#define D_ 6

#define TPB 256
#define NW  4     // waves per block
#define CPS 16    // capsules per wave
#define PF  8     // votes prefetch depth (iterations)

static __device__ __forceinline__ float2 ld2(const float* p) {
    return *reinterpret_cast<const float2*>(p);
}

// Output layout (flat, return order), all float32
static constexpr long OFF_VP   = 1;
static constexpr long OFF_WIN  = OFF_VP   + (long)B_*C_*N_;
static constexpr long OFF_WINP = OFF_WIN  + (long)B_*N_*D_;
static constexpr long OFF_IFC  = OFF_WINP + (long)B_*N_;
static constexpr long OFF_ML   = OFF_IFC  + (long)B_*N_;
static constexpr long OFF_MLP  = OFF_ML   + (long)B_*(C_+1)*N_;
static constexpr long OFF_SW   = OFF_MLP  + (long)B_*(C_+1)*N_;
static constexpr long OFF_SWP  = OFF_SW   + (long)B_*N_*D_;
static constexpr long OFF_PMP  = OFF_SWP  + (long)B_*N_;
static constexpr long OFF_CAPS = OFF_PMP  + (long)B_*N_*C_;

// ws layout: [0..1024) per-block lse sums; [1024 ..) per-(block,c) caps max of vpp
#define WS_CAPS 1024

__global__ __launch_bounds__(TPB, 4) void capsule_main(
    const float* __restrict__ x,
    const float* __restrict__ votes,
    const float* __restrict__ scale,
    const float* __restrict__ vpp,
    const float* __restrict__ dummy_vote,
    float* __restrict__ out,
    float* __restrict__ ws)
{
    constexpr float DUMMY       = -4.6051702f;   // -2*ln(10)
    constexpr float HALFDLOG2PI =  5.5136312f;   // 0.5*D*ln(2*pi)

    // XCD-chunked swizzle: default dispatch round-robins XCDs (bid%8 = XCD).
    // Remap so each XCD owns a contiguous 128-block n-range: adjacent-n blocks
    // (sharing input lines + misaligned write-boundary lines) stay in one L2.
    const int bid  = (int)((blockIdx.x & 7) * 128 + (blockIdx.x >> 3));   // bijective, 8|1024

    const int tid  = threadIdx.x;
    const int lane = tid & 63;
    const int sub  = tid >> 6;                    // 0..3
    const int idx  = bid * 64 + lane;             // b*N + n
    const int b    = idx >> 11;                   // N_ == 2048 (no b straddle: 64|2048)
    const int n    = idx & (N_ - 1);

    const size_t base  = (size_t)b * (C_ * N_) + n;
    const size_t soff  = (size_t)(sub * CPS) * N_;
    const float* scp   = scale + base + soff;
    const float* ppp   = vpp   + base + soff;
    const float* vbs   = votes + (base + soff) * D_;
    const size_t mlrow = (size_t)b * ((C_ + 1) * N_) + n;

    // batch-issue all scale/vpp loads upfront (latency batching)
    float sv[CPS], pv[CPS];
#pragma unroll
    for (int j = 0; j < CPS; ++j) {
        sv[j] = scp[(size_t)j * N_];
        pv[j] = ppp[(size_t)j * N_];
    }

    const float* xp = x + (size_t)idx * D_;
    const float2 xa = ld2(xp), xb = ld2(xp + 2), xc = ld2(xp + 4);

    // votes software pipeline, depth PF, static slot indexing
    float2 va0[PF], va1[PF], va2[PF];
#pragma unroll
    for (int j = 0; j < PF; ++j) {
        const float* vp = vbs + (size_t)j * (N_ * D_);
        va0[j] = ld2(vp); va1[j] = ld2(vp + 2); va2[j] = ld2(vp + 4);
    }

    // LDS: lred/lbc for cross-sub combine; lpmp stages unnormalized e; linv per-point 1/sum
    __shared__ float lred[17 * TPB];
    __shared__ int   lbc[TPB];
    __shared__ float lpmp[64 * 65];
    __shared__ float linv[64];

    // sub 0 seeds the dummy contributions
    float s_pp = 0.0f, s_p = 0.0f;
    float sw0 = 0.f, sw1 = 0.f, sw2 = 0.f, sw3 = 0.f, sw4 = 0.f, sw5 = 0.f;
    if (sub == 0) {
        const float* dp = dummy_vote + (size_t)n * D_;
        const float2 da = ld2(dp), db = ld2(dp + 2), dc = ld2(dp + 4);
        s_pp = 0.01f;            // exp(DUMMY)
        s_p  = 1.0e-4f;          // exp(2*DUMMY)
        sw0 = 1.0e-4f * da.x; sw1 = 1.0e-4f * da.y;
        sw2 = 1.0e-4f * db.x; sw3 = 1.0e-4f * db.y;
        sw4 = 1.0e-4f * dc.x; sw5 = 1.0e-4f * dc.y;
    }
    float swp = 0.0f;
    float best = -3.4e38f, winp = 0.0f;
    float w0=0.f,w1=0.f,w2=0.f,w3=0.f,w4=0.f,w5=0.f;
    int bc = 0;

    float mlv[CPS];   // ml buffered; ML/VP stores batched post-loop (pure-load loop)

#pragma unroll
    for (int j = 0; j < CPS; ++j) {
        const int c  = sub * CPS + j;
        const int sl = j % PF;
        const float2 A = va0[sl], Bv = va1[sl], Cv = va2[sl];
        if (j + PF < CPS) {                       // compile-time per unrolled iter
            const float* vp = vbs + (size_t)(j + PF) * (N_ * D_);
            va0[sl] = ld2(vp); va1[sl] = ld2(vp + 2); va2[sl] = ld2(vp + 4);
        }
        const float s = sv[j];
        const float p = pv[j];
        const float inv = 1.0f / s;
        const float z0 = (xa.x - A.x)  * inv;
        const float z1 = (xa.y - A.y)  * inv;
        const float z2 = (xb.x - Bv.x) * inv;
        const float z3 = (xb.y - Bv.y) * inv;
        const float z4 = (xc.x - Cv.x) * inv;
        const float z5 = (xc.y - Cv.y) * inv;
        float q = z0 * z0;
        q = fmaf(z1, z1, q); q = fmaf(z2, z2, q);
        q = fmaf(z3, z3, q); q = fmaf(z4, z4, q);
        q = fmaf(z5, z5, q);
        const float vlp = fmaf(-0.5f, q, fmaf(-6.0f, __logf(s), -HALFDLOG2PI));
        const float ml  = __logf(p + 1e-16f);
        mlv[j] = ml;
        const float pc = ml + vlp;
        const float e  = __expf(pc);
        lpmp[lane * 65 + c] = e;                  // stage unnormalized; scaled at flush
        s_pp += p + 1e-16f;
        s_p  += e;
        sw0 = fmaf(e, A.x,  sw0); sw1 = fmaf(e, A.y,  sw1);
        sw2 = fmaf(e, Bv.x, sw2); sw3 = fmaf(e, Bv.y, sw3);
        sw4 = fmaf(e, Cv.x, sw4); sw5 = fmaf(e, Cv.y, sw5);
        swp = fmaf(e, p, swp);
        const bool better = pc > best;            // strict > keeps first occurrence
        best = better ? pc : best;
        bc   = better ? c  : bc;
        w0 = better ? A.x  : w0; w1 = better ? A.y  : w1;
        w2 = better ? Bv.x : w2; w3 = better ? Bv.y : w3;
        w4 = better ? Cv.x : w4; w5 = better ? Cv.y : w5;
        winp = better ? p : winp;
    }

    // ---- batched ML + VP stores (streaming, no load interleave) ----
#pragma unroll
    for (int j = 0; j < CPS; ++j) {
        const int c  = sub * CPS + j;
        const float ml = mlv[j];
        out[OFF_ML + mlrow + (size_t)c * N_] = ml;                          // coalesced over n
        out[OFF_VP + ((size_t)(b * C_ + c)) * N_ + n] = (DUMMY < ml) ? 1.0f : 0.0f;
    }

    // ---- cross-sub combine via LDS ----
#define LR(e) lred[(e) * TPB + sub * 64 + lane]
    LR(0) = s_p;
    LR(1) = sw0; LR(2) = sw1; LR(3) = sw2; LR(4) = sw3; LR(5) = sw4; LR(6) = sw5;
    LR(7) = swp; LR(8) = s_pp;
    LR(9) = best;
    LR(10) = w0; LR(11) = w1; LR(12) = w2; LR(13) = w3; LR(14) = w4; LR(15) = w5;
    LR(16) = winp;
    lbc[sub * 64 + lane] = bc;
#undef LR
    __syncthreads();

#define LS(e, s) lred[(e) * TPB + (s) * 64 + lane]
    float c_sp  = LS(0,0) + LS(0,1) + LS(0,2) + LS(0,3);
    float c_sw0 = LS(1,0) + LS(1,1) + LS(1,2) + LS(1,3);
    float c_sw1 = LS(2,0) + LS(2,1) + LS(2,2) + LS(2,3);
    float c_sw2 = LS(3,0) + LS(3,1) + LS(3,2) + LS(3,3);
    float c_sw3 = LS(4,0) + LS(4,1) + LS(4,2) + LS(4,3);
    float c_sw4 = LS(5,0) + LS(5,1) + LS(5,2) + LS(5,3);
    float c_sw5 = LS(6,0) + LS(6,1) + LS(6,2) + LS(6,3);
    float c_swp = LS(7,0) + LS(7,1) + LS(7,2) + LS(7,3);
    float c_spp = LS(8,0) + LS(8,1) + LS(8,2) + LS(8,3);
    float g_best = LS(9,0);
    int   g_bc   = lbc[lane];
    float g_w0 = LS(10,0), g_w1 = LS(11,0), g_w2 = LS(12,0),
          g_w3 = LS(13,0), g_w4 = LS(14,0), g_w5 = LS(15,0);
    float g_winp = LS(16,0);
#pragma unroll
    for (int s = 1; s < NW; ++s) {
        const float cb = LS(9, s);
        if (cb > g_best) {                      // strict >: earliest sub wins ties
            g_best = cb;
            g_bc   = lbc[s * 64 + lane];
            g_w0 = LS(10,s); g_w1 = LS(11,s); g_w2 = LS(12,s);
            g_w3 = LS(13,s); g_w4 = LS(14,s); g_w5 = LS(15,s);
            g_winp = LS(16,s);
        }
    }
#undef LS

    const float lse_ml = __logf(c_spp);
    const float lse_p  = __logf(c_sp);
    const float inv_sp = 1.0f / c_sp;

    if (sub == 0) {
        linv[lane] = inv_sp;
        out[OFF_ML  + mlrow + (size_t)C_ * N_] = DUMMY;
        out[OFF_MLP + mlrow + (size_t)C_ * N_] = DUMMY - lse_ml;
        float* wq = out + OFF_WIN + (size_t)idx * D_;
        wq[0] = g_w0; wq[1] = g_w1; wq[2] = g_w2;
        wq[3] = g_w3; wq[4] = g_w4; wq[5] = g_w5;
        out[OFF_WINP + idx] = g_winp;
        out[OFF_IFC + idx]  = 0.0f;               // g_bc < 64 < N -> always 0
        float* sq = out + OFF_SW + (size_t)idx * D_;
        sq[0] = c_sw0 * inv_sp; sq[1] = c_sw1 * inv_sp; sq[2] = c_sw2 * inv_sp;
        sq[3] = c_sw3 * inv_sp; sq[4] = c_sw4 * inv_sp; sq[5] = c_sw5 * inv_sp;
        out[OFF_SWP + idx] = c_swp * inv_sp;
        // per-block lse sum for log_prob
        float v = lse_p;
#pragma unroll
        for (int m = 32; m > 0; m >>= 1)
            v += __shfl_xor(v, m, 64);
        if (lane == 0) ws[bid] = v;
    }

    // mixing_log_prob for this sub's capsules (from buffered mlv)
#pragma unroll
    for (int j = 0; j < CPS; ++j) {
        const int c = sub * CPS + j;
        out[OFF_MLP + mlrow + (size_t)c * N_] = mlv[j] - lse_ml;
    }

    __syncthreads();   // lpmp complete + linv visible

    // posterior_mixing_probs flush: coalesced, normalized by the owning point's inv_sp
    {
        const size_t pbase = OFF_PMP + (size_t)bid * (64 * C_);
#pragma unroll
        for (int k = 0; k < (64 * C_) / TPB; ++k) {
            const int g = tid + k * TPB;
            const int p = g >> 6, cc = g & 63;
            out[pbase + g] = lpmp[p * 65 + cc] * linv[p];
        }
    }

    // caps_presence partial max over this block's 64 n's (post-loop, from live pv)
    {
        const size_t capsbase = WS_CAPS + (size_t)bid * C_ + sub * CPS;
#pragma unroll
        for (int j = 0; j < CPS; ++j) {
            float m = pv[j];
#pragma unroll
            for (int q2 = 32; q2 > 0; q2 >>= 1)
                m = fmaxf(m, __shfl_xor(m, q2, 64));
            if (lane == 0) ws[capsbase + j] = m;
        }
    }
}

// block 0: log_prob reduce; blocks 1..32: caps_presence_prob for b = blockIdx-1
__global__ __launch_bounds__(256) void capsule_finish(
    const float* __restrict__ ws, float* __restrict__ out)
{
    const int tid = threadIdx.x;
    if (blockIdx.x == 0) {
        __shared__ float red[256];
        red[tid] = ws[tid] + ws[tid + 256] + ws[tid + 512] + ws[tid + 768];
        __syncthreads();
#pragma unroll
        for (int off2 = 128; off2 > 0; off2 >>= 1) {
            if (tid < off2) red[tid] += red[tid + off2];
            __syncthreads();
        }
        if (tid == 0) out[0] = red[0] * (1.0f / (float)B_);
    } else {
        const int b = blockIdx.x - 1;
        const int c = tid & 63, q = tid >> 6;          // q: 0..3, 8 partials each
        const float* cp = ws + WS_CAPS;
        float m = -3.4e38f;
#pragma unroll
        for (int r = 0; r < 8; ++r)
            m = fmaxf(m, cp[(size_t)(b * 32 + q * 8 + r) * C_ + c]);
        __shared__ float red4[4 * 64];
        red4[q * 64 + c] = m;
        __syncthreads();
        if (tid < 64) {
            float mm = fmaxf(fmaxf(red4[tid], red4[64 + tid]),
                             fmaxf(red4[128 + tid], red4[192 + tid]));
            out[OFF_CAPS + (size_t)b * C_ + tid] = mm;
        }
    }
}

extern "C" void kernel_launch(void* const* d_in, const int* in_sizes, int n_in,
                              void* d_out, int out_size, void* d_ws, size_t ws_size,
                              hipStream_t stream) {
    const float* x     = (const float*)d_in[0];
    const float* votes = (const float*)d_in[1];
    const float* scale = (const float*)d_in[2];
    const float* vpp   = (const float*)d_in[3];
    const float* dummy = (const float*)d_in[4];
    float* out = (float*)d_out;
    float* ws  = (float*)d_ws;   // 1024 + 1024*64 floats (= 260 KB)

    capsule_main<<<(B_ * N_) / 64, TPB, 0, stream>>>(x, votes, scale, vpp, dummy, out, ws);
    capsule_finish<<<1 + B_, 256, 0, stream>>>(ws, out);
}